// Round 14
// baseline (637.439 us; speedup 1.0000x reference)
//
#include <hip/hip_runtime.h>
#include <cstdint>
#include <cstddef>

#define NB 16
#define TT 12
#define NN 1024
#define DD 64
#define FF 64
#define JT 768   // T*D

typedef __attribute__((ext_vector_type(8))) short v8s;
typedef __attribute__((ext_vector_type(4))) short v4s;
typedef __attribute__((ext_vector_type(4))) float v4f;

__device__ __forceinline__ float sigmoidf_(float v) { return 1.0f / (1.0f + expf(-v)); }
__device__ __forceinline__ float fsig(float v) {
    return __fdividef(1.0f, 1.0f + __expf(-v));
}
__device__ __forceinline__ float ftanh(float v) {
    v = fminf(fmaxf(v, -15.0f), 15.0f);
    const float e = __expf(2.0f * v);
    return __fdividef(e - 1.0f, e + 1.0f);
}

__device__ __forceinline__ float bf2f(unsigned short h) {
    union { unsigned int u; float f; } x; x.u = ((unsigned int)h) << 16; return x.f;
}
__device__ __forceinline__ unsigned short f2bf(float f) {
    union { float f; unsigned int u; } x; x.f = f;
    return (unsigned short)((x.u + 0x7fffu + ((x.u >> 16) & 1u)) >> 16);
}

__device__ __forceinline__ void gload16(const void* g, void* lds) {
    __builtin_amdgcn_global_load_lds(
        (const __attribute__((address_space(1))) void*)g,
        (__attribute__((address_space(3))) void*)lds, 16, 0, 0);
}

// ---------------- split A (fp32 row-major) -> Ah, Al bf16 row-major ----------
__global__ __launch_bounds__(256) void split_A(
    const float* __restrict__ A, unsigned short* __restrict__ Ah,
    unsigned short* __restrict__ Al)
{
    const size_t i0 = ((size_t)blockIdx.x * 256 + threadIdx.x) * 16;
    float v[16];
#pragma unroll
    for (int s = 0; s < 4; ++s)
        *(float4*)&v[s * 4] = *(const float4*)&A[i0 + s * 4];
    v8s h0, h1, l0, l1;
#pragma unroll
    for (int q = 0; q < 8; ++q) {
        unsigned short h = f2bf(v[q]);
        h0[q] = (short)h; l0[q] = (short)f2bf(v[q] - bf2f(h));
    }
#pragma unroll
    for (int q = 0; q < 8; ++q) {
        unsigned short h = f2bf(v[8 + q]);
        h1[q] = (short)h; l1[q] = (short)f2bf(v[8 + q] - bf2f(h));
    }
    *(v8s*)&Ah[i0] = h0; *(v8s*)&Ah[i0 + 8] = h1;
    *(v8s*)&Al[i0] = l0; *(v8s*)&Al[i0 + 8] = l1;
}

// ------ split+transpose x (B,T,N,D) fp32 -> xTh,xTl (B, 768, 1024) bf16 ------
__global__ __launch_bounds__(256) void xsplitT(
    const float* __restrict__ x, unsigned short* __restrict__ Th,
    unsigned short* __restrict__ Tl)
{
    __shared__ float tile[64][68];
    const int v0 = blockIdx.x * 64, t = blockIdx.y, b = blockIdx.z;
    const int tid = threadIdx.x;
    {
        const int r = tid >> 2, q = (tid & 3) * 16;
#pragma unroll
        for (int s = 0; s < 4; ++s) {
            const float4 w = *(const float4*)&x[(((size_t)b * TT + t) * NN + v0 + r) * DD + q + s * 4];
            tile[r][q + s * 4 + 0] = w.x; tile[r][q + s * 4 + 1] = w.y;
            tile[r][q + s * 4 + 2] = w.z; tile[r][q + s * 4 + 3] = w.w;
        }
    }
    __syncthreads();
    {
        const int d = tid >> 2, vc = (tid & 3) * 16;
        const size_t base = ((size_t)b * JT + t * 64 + d) * 1024 + v0 + vc;
        v8s h0, h1, l0, l1;
#pragma unroll
        for (int s = 0; s < 8; ++s) {
            const float f = tile[vc + s][d];
            unsigned short h = f2bf(f);
            h0[s] = (short)h; l0[s] = (short)f2bf(f - bf2f(h));
        }
#pragma unroll
        for (int s = 0; s < 8; ++s) {
            const float f = tile[vc + 8 + s][d];
            unsigned short h = f2bf(f);
            h1[s] = (short)h; l1[s] = (short)f2bf(f - bf2f(h));
        }
        *(v8s*)&Th[base] = h0; *(v8s*)&Th[base + 8] = h1;
        *(v8s*)&Tl[base] = l0; *(v8s*)&Tl[base + 8] = l1;
    }
}

// -------- bf16 split-2 MFMA GEMM: C[b][n][m] = sum_k A[b][m][k] * B[b][n][k] --
// 128m x 192n tiles -> grid 512 = exactly 2 blocks/CU, no tail.
// 3 products: AhBh + AhBl + AlBh (al*bl dropped: measured cost <=1e-3 absmax).
template<bool PAIROUT>
__global__ __launch_bounds__(256, 2) void gemm_bf(
    const unsigned short* __restrict__ Ah, const unsigned short* __restrict__ Al,
    const unsigned short* __restrict__ Bh, const unsigned short* __restrict__ Bl,
    unsigned short* __restrict__ Ch, unsigned short* __restrict__ Cl,
    float* __restrict__ Cf)
{
    __shared__ unsigned short LA[2][2][4096];   // [buf][hi/lo][128m x 32k]
    __shared__ unsigned short LB[2][2][6144];   // [buf][hi/lo][192n x 32k]

    const int wg = blockIdx.x;
    const int nlin = (wg & 7) * 64 + (wg >> 3);
    const int b  = nlin >> 5;
    const int rr = nlin & 31;
    const int m0 = (rr >> 2) * 128, n0 = (rr & 3) * 192;

    const int tid = threadIdx.x, lane = tid & 63, wid = tid >> 6;
    const int lr = lane & 15, hi = lane >> 4;
    const int wr = wid >> 1, wc = wid & 1;

    auto stage = [&](int buf, int kt) {
        const int rA = lane >> 2, kc = (lane & 3) * 8;
#pragma unroll
        for (int p = 0; p < 2; ++p) {
            const int c = wid * 2 + p;
            const size_t ga = ((size_t)b * 1024 + m0 + c * 16 + rA) * 1024 + kt * 32 + kc;
            gload16(Ah + ga, &LA[buf][0][c * 512]);
            gload16(Al + ga, &LA[buf][1][c * 512]);
        }
#pragma unroll
        for (int p = 0; p < 3; ++p) {
            const int c = wid * 3 + p;
            const size_t gb = ((size_t)b * JT + n0 + c * 16 + rA) * 1024 + kt * 32 + kc;
            gload16(Bh + gb, &LB[buf][0][c * 512]);
            gload16(Bl + gb, &LB[buf][1][c * 512]);
        }
    };

    v4f acc[4][6];
#pragma unroll
    for (int i = 0; i < 4; ++i)
#pragma unroll
        for (int j = 0; j < 6; ++j) acc[i][j] = (v4f){0.f, 0.f, 0.f, 0.f};

    stage(0, 0);
    __syncthreads();
    int cur = 0;
    for (int kt = 0; kt < 32; ++kt) {
        if (kt + 1 < 32) stage(cur ^ 1, kt + 1);
        v8s ah[4], al[4], bh[6], bl[6];
#pragma unroll
        for (int f = 0; f < 4; ++f) {
            const int m = wr * 64 + f * 16 + lr;
            ah[f] = *(const v8s*)&LA[cur][0][m * 32 + hi * 8];
            al[f] = *(const v8s*)&LA[cur][1][m * 32 + hi * 8];
        }
#pragma unroll
        for (int f = 0; f < 6; ++f) {
            const int n = wc * 96 + f * 16 + lr;
            bh[f] = *(const v8s*)&LB[cur][0][n * 32 + hi * 8];
            bl[f] = *(const v8s*)&LB[cur][1][n * 32 + hi * 8];
        }
#pragma unroll
        for (int fi = 0; fi < 4; ++fi)
#pragma unroll
            for (int fj = 0; fj < 6; ++fj) {
                acc[fi][fj] = __builtin_amdgcn_mfma_f32_16x16x32_bf16(ah[fi], bh[fj], acc[fi][fj], 0, 0, 0);
                acc[fi][fj] = __builtin_amdgcn_mfma_f32_16x16x32_bf16(ah[fi], bl[fj], acc[fi][fj], 0, 0, 0);
                acc[fi][fj] = __builtin_amdgcn_mfma_f32_16x16x32_bf16(al[fi], bh[fj], acc[fi][fj], 0, 0, 0);
            }
        __syncthreads();
        cur ^= 1;
    }

#pragma unroll
    for (int fi = 0; fi < 4; ++fi)
#pragma unroll
        for (int fj = 0; fj < 6; ++fj) {
            const int n  = n0 + wc * 96 + fj * 16 + lr;
            const int mb = m0 + wr * 64 + fi * 16 + hi * 4;
            const size_t o = ((size_t)b * JT + n) * 1024 + mb;
            if (PAIROUT) {
                v4s vh, vl;
#pragma unroll
                for (int r = 0; r < 4; ++r) {
                    const float v = acc[fi][fj][r];
                    const unsigned short h = f2bf(v);
                    vh[r] = (short)h; vl[r] = (short)f2bf(v - bf2f(h));
                }
                *(v4s*)&Ch[o] = vh;
                *(v4s*)&Cl[o] = vl;
            } else {
                float4 v = {acc[fi][fj][0], acc[fi][fj][1], acc[fi][fj][2], acc[fi][fj][3]};
                *(float4*)&Cf[o] = v;
            }
        }
}

// -------------- fallback fp32 GEMM --------
template<bool XFROMX>
__global__ __launch_bounds__(256, 4) void gemm_f32(
    const float* __restrict__ Aop, const float* __restrict__ Xin,
    float* __restrict__ Xout)
{
    __shared__ float As[2][16 * 132];
    __shared__ float Bs[2][16 * 128];
    const int wg  = blockIdx.x;
    const int nlin = (wg & 7) * 96 + (wg >> 3);
    const int b  = nlin / 48;
    const int rr = nlin % 48;
    const int rb = rr / 6, cb = rr % 6;
    const int w0 = rb * 128, j0 = cb * 128;
    const int tid = threadIdx.x;
    const int rg = tid >> 4, cg = tid & 15;
    const int row0 = rg * 8;

    auto stage = [&](int buf, int kt) {
        const float* Ab = Aop + (size_t)b * NN * NN;
#pragma unroll
        for (int p = 0; p < 2; ++p) {
            const int c  = tid + p * 256;
            const int w  = c >> 2;
            const int k4 = (c & 3) * 4;
            const float4 v = *(const float4*)&Ab[(size_t)(w0 + w) * NN + kt * 16 + k4];
            As[buf][(k4 + 0) * 132 + w] = v.x;
            As[buf][(k4 + 1) * 132 + w] = v.y;
            As[buf][(k4 + 2) * 132 + w] = v.z;
            As[buf][(k4 + 3) * 132 + w] = v.w;
        }
#pragma unroll
        for (int p = 0; p < 2; ++p) {
            const int c = tid + p * 256;
            const int k = c >> 5;
            const int j = (c & 31) * 4;
            float4 v;
            if (XFROMX) {
                const int t = cb * 2 + (j >> 6);
                const int d = j & 63;
                v = *(const float4*)&Xin[(((size_t)b * TT + t) * NN + (size_t)kt * 16 + k) * DD + d];
            } else {
                v = *(const float4*)&Xin[((size_t)b * NN + (size_t)kt * 16 + k) * JT + j0 + j];
            }
            *(float4*)&Bs[buf][k * 128 + j] = v;
        }
    };

    float acc[8][8];
#pragma unroll
    for (int i = 0; i < 8; ++i)
#pragma unroll
        for (int j = 0; j < 8; ++j) acc[i][j] = 0.0f;

    stage(0, 0);
    __syncthreads();
    int cur = 0;
    for (int kt = 0; kt < 64; ++kt) {
        if (kt + 1 < 64) stage(cur ^ 1, kt + 1);
#pragma unroll
        for (int k = 0; k < 16; ++k) {
            float a[8], bb[8];
            *(float4*)&a[0]  = *(const float4*)&As[cur][k * 132 + row0];
            *(float4*)&a[4]  = *(const float4*)&As[cur][k * 132 + row0 + 4];
            *(float4*)&bb[0] = *(const float4*)&Bs[cur][k * 128 + cg * 4];
            *(float4*)&bb[4] = *(const float4*)&Bs[cur][k * 128 + 64 + cg * 4];
#pragma unroll
            for (int i = 0; i < 8; ++i)
#pragma unroll
                for (int j = 0; j < 8; ++j)
                    acc[i][j] = fmaf(a[i], bb[j], acc[i][j]);
        }
        __syncthreads();
        cur ^= 1;
    }
#pragma unroll
    for (int i = 0; i < 8; ++i) {
        float4 v0 = {acc[i][0], acc[i][1], acc[i][2], acc[i][3]};
        float4 v1 = {acc[i][4], acc[i][5], acc[i][6], acc[i][7]};
        float* dst = Xout + ((size_t)b * NN + w0 + row0 + i) * JT + j0;
        *(float4*)&dst[cg * 4]      = v0;
        *(float4*)&dst[64 + cg * 4] = v1;
    }
}

// ---------------- conv (BTN x 192 @ 192 x 64) + BN + ReLU -> fp32 y ---------
template<bool PAIRS>
__global__ __launch_bounds__(256) void conv_bn_relu(
    const float* __restrict__ x,
    const unsigned short* __restrict__ X1h, const unsigned short* __restrict__ X1l,
    const float* __restrict__ X2T,
    const float* __restrict__ X1f, const float* __restrict__ X2f,
    const float* __restrict__ W,
    const float* __restrict__ convb, const float* __restrict__ gamma,
    const float* __restrict__ beta,  const float* __restrict__ mean,
    const float* __restrict__ var,   float* __restrict__ y)
{
    __shared__ float As[64][132];
    __shared__ float Ws[64][68];
    const int nb = blockIdx.x, t = blockIdx.y, b = blockIdx.z;
    const int n0 = nb * 128;
    const int tid = threadIdx.x;
    const int rg = tid >> 4, cg = tid & 15;
    const int row0 = rg * 8, f0 = cg * 4;

    float acc[8][4];
#pragma unroll
    for (int i = 0; i < 8; ++i)
#pragma unroll
        for (int j = 0; j < 4; ++j) acc[i][j] = 0.0f;

    for (int kt = 0; kt < 3; ++kt) {
        __syncthreads();
        if (kt == 0) {
            const float* src = x + (((size_t)b * TT + t) * NN + n0) * DD;
#pragma unroll
            for (int p = 0; p < 8; ++p) {
                const int row = (tid >> 4) + p * 16;
                const int c4  = (tid & 15) * 4;
                const float4 v = *(const float4*)&src[(size_t)row * DD + c4];
                As[c4 + 0][row] = v.x; As[c4 + 1][row] = v.y;
                As[c4 + 2][row] = v.z; As[c4 + 3][row] = v.w;
            }
        } else if (PAIRS) {
            if (kt == 1) {
#pragma unroll
                for (int p = 0; p < 4; ++p) {
                    const int pos = p * 256 + tid;
                    const int c = pos >> 4, rw = (pos & 15) * 8;
                    const size_t o = ((size_t)b * JT + t * 64 + c) * 1024 + n0 + rw;
                    const v8s hv = *(const v8s*)&X1h[o];
                    const v8s lv = *(const v8s*)&X1l[o];
#pragma unroll
                    for (int q = 0; q < 8; ++q)
                        As[c][rw + q] = bf2f((unsigned short)hv[q]) + bf2f((unsigned short)lv[q]);
                }
            } else {
#pragma unroll
                for (int p = 0; p < 8; ++p) {
                    const int pos = p * 256 + tid;
                    const int c = pos >> 5, rw = (pos & 31) * 4;
                    const float4 v = *(const float4*)&X2T[((size_t)b * JT + t * 64 + c) * 1024 + n0 + rw];
                    As[c][rw + 0] = v.x; As[c][rw + 1] = v.y;
                    As[c][rw + 2] = v.z; As[c][rw + 3] = v.w;
                }
            }
        } else {
            const float* src = ((kt == 1) ? X1f : X2f) + ((size_t)b * NN + n0) * JT + t * DD;
#pragma unroll
            for (int p = 0; p < 8; ++p) {
                const int row = (tid >> 4) + p * 16;
                const int c4  = (tid & 15) * 4;
                const float4 v = *(const float4*)&src[(size_t)row * JT + c4];
                As[c4 + 0][row] = v.x; As[c4 + 1][row] = v.y;
                As[c4 + 2][row] = v.z; As[c4 + 3][row] = v.w;
            }
        }
#pragma unroll
        for (int p = 0; p < 4; ++p) {
            const int f  = (tid >> 4) + p * 16;
            const int c4 = (tid & 15) * 4;
            const float4 v = *(const float4*)&W[f * 192 + kt * 64 + c4];
            Ws[c4 + 0][f] = v.x; Ws[c4 + 1][f] = v.y;
            Ws[c4 + 2][f] = v.z; Ws[c4 + 3][f] = v.w;
        }
        __syncthreads();
#pragma unroll
        for (int k = 0; k < 64; ++k) {
            float a[8], w[4];
            *(float4*)&a[0] = *(const float4*)&As[k][row0];
            *(float4*)&a[4] = *(const float4*)&As[k][row0 + 4];
            *(float4*)&w[0] = *(const float4*)&Ws[k][f0];
#pragma unroll
            for (int i = 0; i < 8; ++i)
#pragma unroll
                for (int j = 0; j < 4; ++j)
                    acc[i][j] = fmaf(a[i], w[j], acc[i][j]);
        }
    }
    float s[4], off[4];
#pragma unroll
    for (int j = 0; j < 4; ++j) {
        const int f = f0 + j;
        const float sc = gamma[f] / sqrtf(var[f] + 1e-5f);
        s[j]   = sc;
        off[j] = (convb[f] - mean[f]) * sc + beta[f];
    }
#pragma unroll
    for (int i = 0; i < 8; ++i) {
        float4 v;
        v.x = fmaxf(acc[i][0] * s[0] + off[0], 0.0f);
        v.y = fmaxf(acc[i][1] * s[1] + off[1], 0.0f);
        v.z = fmaxf(acc[i][2] * s[2] + off[2], 0.0f);
        v.w = fmaxf(acc[i][3] * s[3] + off[3], 0.0f);
        *(float4*)&y[(((size_t)b * TT + t) * NN + n0 + row0 + i) * FF + f0] = v;
    }
}

// ------- GRU weight prep: 5 bf16 planes per t for ru (WF) and z (WZ) --------
__global__ __launch_bounds__(256) void wprep3(
    const float* __restrict__ wff, const float* __restrict__ wzff,
    unsigned short* __restrict__ WF, unsigned short* __restrict__ WZ)
{
    const int t = blockIdx.x;
    unsigned short* F = WF + (size_t)t * 40960;
    for (int e = threadIdx.x; e < 8192; e += 256) {
        const int o = e >> 6, k = e & 63;
        const float vx = wff[((size_t)t * 128 + k) * 128 + o];
        const unsigned short xh = f2bf(vx);
        const float r1 = vx - bf2f(xh);
        const unsigned short xm = f2bf(r1);
        const unsigned short xl = f2bf(r1 - bf2f(xm));
        F[0 * 8192 + o * 64 + k] = xh;
        F[1 * 8192 + o * 64 + k] = xm;
        F[2 * 8192 + o * 64 + k] = xl;
        const float vh = wff[((size_t)t * 128 + 64 + k) * 128 + o];
        const unsigned short hh = f2bf(vh);
        const unsigned short hl = f2bf(vh - bf2f(hh));
        F[3 * 8192 + o * 64 + k] = hh;
        F[4 * 8192 + o * 64 + k] = hl;
    }
    unsigned short* Z = WZ + (size_t)t * 20480;
    for (int e = threadIdx.x; e < 4096; e += 256) {
        const int o = e >> 6, k = e & 63;
        const float vx = wzff[((size_t)t * 128 + k) * 64 + o];
        const unsigned short xh = f2bf(vx);
        const float r1 = vx - bf2f(xh);
        const unsigned short xm = f2bf(r1);
        const unsigned short xl = f2bf(r1 - bf2f(xm));
        Z[0 * 4096 + o * 64 + k] = xh;
        Z[1 * 4096 + o * 64 + k] = xm;
        Z[2 * 4096 + o * 64 + k] = xl;
        const float vr = wzff[((size_t)t * 128 + 64 + k) * 64 + o];
        const unsigned short rh = f2bf(vr);
        const unsigned short rl = f2bf(vr - bf2f(rh));
        Z[3 * 4096 + o * 64 + k] = rh;
        Z[4 * 4096 + o * 64 + k] = rl;
    }
}

// ------ fused GRU v10: gru7's exact schedule, distributed over 8 waves ------
// Same 512 blocks x 32 rows; 512 threads (8 waves) per block. Each wave owns
// ONE ru o-slice (o = w*16+lr) instead of two -> per-wave serial work halves,
// waves/SIMD 2->4 (latency hiding). Total MFMA / weight-load / barrier counts
// per SIMD unchanged; per-output arithmetic order identical to gru7.
// r-owners: w<4 (o<64); u-owners: w>=4. z o-slice: (w&3)*16+lr (2x duplicated
// as before). Barriers: SYNC_C, SYNC_F only.
__global__ __launch_bounds__(512, 4) void gru10(
    const float* __restrict__ y,
    const unsigned short* __restrict__ WF, const unsigned short* __restrict__ WZ,
    const float* __restrict__ bff, const float* __restrict__ bzff,
    float* __restrict__ out)
{
    __shared__ unsigned short Ahp[4096];   // h pairs   [m 32][{h[64]|l[64]}] ^ ((m&7)<<3)
    __shared__ unsigned short Rhp[4096];   // r*h pairs same layout
    __shared__ float Hs[32][68];           // fp32 h state

    const int tid = threadIdx.x, lane = tid & 63, w = tid >> 6;   // w in 0..7
    const int lr = lane & 15, hi = lane >> 4;
    const int b = blockIdx.x >> 5, n0 = (blockIdx.x & 31) * 32;

    for (int i = tid; i < 4096; i += 512) { Ahp[i] = 0; Rhp[i] = 0; }
    for (int i = tid; i < 32 * 68; i += 512) (&Hs[0][0])[i] = 0.0f;
    __syncthreads();

    auto loadx = [&](int t, v8s xa[2][2][3]) {
        const float* yb = y + (((size_t)b * TT + t) * NN + n0) * 64;
#pragma unroll
        for (int mf = 0; mf < 2; ++mf)
#pragma unroll
            for (int kc = 0; kc < 2; ++kc) {
                const int m = mf * 16 + lr;
                float xv[8];
                *(float4*)&xv[0] = *(const float4*)&yb[m * 64 + kc * 32 + hi * 8];
                *(float4*)&xv[4] = *(const float4*)&yb[m * 64 + kc * 32 + hi * 8 + 4];
                v8s h3, m3, l3;
#pragma unroll
                for (int q = 0; q < 8; ++q) {
                    const float v = xv[q];
                    const unsigned short hh = f2bf(v);
                    const float r1 = v - bf2f(hh);
                    const unsigned short mm = f2bf(r1);
                    const unsigned short ll = f2bf(r1 - bf2f(mm));
                    h3[q] = (short)hh; m3[q] = (short)mm; l3[q] = (short)ll;
                }
                xa[mf][kc][0] = h3; xa[mf][kc][1] = m3; xa[mf][kc][2] = l3;
            }
    };
    auto xru_mfma = [&](int t, const v8s xa[2][2][3], v4f xacc[2]) {
        const int o = w * 16 + lr;
        v8s wx[2][3];
#pragma unroll
        for (int kc = 0; kc < 2; ++kc)
#pragma unroll
            for (int lev = 0; lev < 3; ++lev)
                wx[kc][lev] = *(const v8s*)&WF[((size_t)t * 5 + lev) * 8192 + o * 64 + kc * 32 + hi * 8];
#pragma unroll
        for (int mf = 0; mf < 2; ++mf)
#pragma unroll
            for (int kc = 0; kc < 2; ++kc) {
                v4f a = xacc[mf];
                a = __builtin_amdgcn_mfma_f32_16x16x32_bf16(xa[mf][kc][0], wx[kc][0], a, 0, 0, 0);
                a = __builtin_amdgcn_mfma_f32_16x16x32_bf16(xa[mf][kc][0], wx[kc][1], a, 0, 0, 0);
                a = __builtin_amdgcn_mfma_f32_16x16x32_bf16(xa[mf][kc][1], wx[kc][0], a, 0, 0, 0);
                a = __builtin_amdgcn_mfma_f32_16x16x32_bf16(xa[mf][kc][0], wx[kc][2], a, 0, 0, 0);
                a = __builtin_amdgcn_mfma_f32_16x16x32_bf16(xa[mf][kc][1], wx[kc][1], a, 0, 0, 0);
                a = __builtin_amdgcn_mfma_f32_16x16x32_bf16(xa[mf][kc][2], wx[kc][0], a, 0, 0, 0);
                xacc[mf] = a;
            }
    };
    auto xz_mfma = [&](int t, const v8s xa[2][2][3], v4f xacc[2]) {
        const int o = (w & 3) * 16 + lr;
        v8s wx[2][3];
#pragma unroll
        for (int kc = 0; kc < 2; ++kc)
#pragma unroll
            for (int lev = 0; lev < 3; ++lev)
                wx[kc][lev] = *(const v8s*)&WZ[((size_t)t * 5 + lev) * 4096 + o * 64 + kc * 32 + hi * 8];
#pragma unroll
        for (int mf = 0; mf < 2; ++mf)
#pragma unroll
            for (int kc = 0; kc < 2; ++kc) {
                v4f a = xacc[mf];
                a = __builtin_amdgcn_mfma_f32_16x16x32_bf16(xa[mf][kc][0], wx[kc][0], a, 0, 0, 0);
                a = __builtin_amdgcn_mfma_f32_16x16x32_bf16(xa[mf][kc][0], wx[kc][1], a, 0, 0, 0);
                a = __builtin_amdgcn_mfma_f32_16x16x32_bf16(xa[mf][kc][1], wx[kc][0], a, 0, 0, 0);
                a = __builtin_amdgcn_mfma_f32_16x16x32_bf16(xa[mf][kc][0], wx[kc][2], a, 0, 0, 0);
                a = __builtin_amdgcn_mfma_f32_16x16x32_bf16(xa[mf][kc][1], wx[kc][1], a, 0, 0, 0);
                a = __builtin_amdgcn_mfma_f32_16x16x32_bf16(xa[mf][kc][2], wx[kc][0], a, 0, 0, 0);
                xacc[mf] = a;
            }
    };

    // prologue: x contributions for t=0
    v4f xru[2], xz[2];
#pragma unroll
    for (int mf = 0; mf < 2; ++mf) {
        xru[mf] = (v4f){0.f, 0.f, 0.f, 0.f};
        xz[mf]  = (v4f){0.f, 0.f, 0.f, 0.f};
    }
    {
        v8s xa0[2][2][3];
        loadx(0, xa0);
        xru_mfma(0, xa0, xru);
        xz_mfma(0, xa0, xz);
    }

    for (int t = 0; t < TT; ++t) {
        const int hasNext = (t + 1 < TT);
        // ---- phase 0: h a-frags from Ahp (ordered before epilogue by SYNC_C)
        v8s ha[2][2][2];
#pragma unroll
        for (int mf = 0; mf < 2; ++mf)
#pragma unroll
            for (int kc = 0; kc < 2; ++kc) {
                const int m = mf * 16 + lr;
                const int base = m * 128 + kc * 32 + hi * 8;
                const int sw = (m & 7) << 3;
                ha[mf][kc][0] = *(const v8s*)&Ahp[base ^ sw];
                ha[mf][kc][1] = *(const v8s*)&Ahp[(base + 64) ^ sw];
            }

        // ---- phase 1: ru = xru (precomputed) + h-part; overlap next-x load + ru
        v4f acc[2];
#pragma unroll
        for (int mf = 0; mf < 2; ++mf) acc[mf] = xru[mf];

        v8s xan[2][2][3];
        v4f xruN[2], xzN[2];
#pragma unroll
        for (int mf = 0; mf < 2; ++mf) {
            xruN[mf] = (v4f){0.f, 0.f, 0.f, 0.f};
            xzN[mf]  = (v4f){0.f, 0.f, 0.f, 0.f};
        }
        if (hasNext) loadx(t + 1, xan);

        {
            const int o = w * 16 + lr;
            v8s wh_[2][2];
#pragma unroll
            for (int kc = 0; kc < 2; ++kc)
#pragma unroll
                for (int lev = 0; lev < 2; ++lev)
                    wh_[kc][lev] = *(const v8s*)&WF[((size_t)t * 5 + 3 + lev) * 8192 + o * 64 + kc * 32 + hi * 8];
#pragma unroll
            for (int mf = 0; mf < 2; ++mf)
#pragma unroll
                for (int kc = 0; kc < 2; ++kc) {
                    v4f a = acc[mf];
                    a = __builtin_amdgcn_mfma_f32_16x16x32_bf16(ha[mf][kc][0], wh_[kc][0], a, 0, 0, 0);
                    a = __builtin_amdgcn_mfma_f32_16x16x32_bf16(ha[mf][kc][0], wh_[kc][1], a, 0, 0, 0);
                    a = __builtin_amdgcn_mfma_f32_16x16x32_bf16(ha[mf][kc][1], wh_[kc][0], a, 0, 0, 0);
                    acc[mf] = a;
                }
        }
        if (hasNext) xru_mfma(t + 1, xan, xruN);   // independent — fills stalls

        // ---- phase 2: activations — waves 0-3 write Rhp (r); waves 4-7 keep u
        float u_[2][4];
        {
            const int o = w * 16 + lr;
            const float bv = bff[(size_t)t * 128 + o];
#pragma unroll
            for (int mf = 0; mf < 2; ++mf)
#pragma unroll
                for (int q = 0; q < 4; ++q) {
                    const float g = fsig(acc[mf][q] + bv);
                    if (w < 4) {
                        const int m = mf * 16 + hi * 4 + q;
                        const float rh = g * Hs[m][o];
                        const unsigned short h = f2bf(rh);
                        const unsigned short l = f2bf(rh - bf2f(h));
                        const int sw = (m & 7) << 3;
                        Rhp[(m * 128 + o) ^ sw]      = h;
                        Rhp[(m * 128 + 64 + o) ^ sw] = l;
                    } else {
                        u_[mf][q] = g;
                    }
                }
        }
        __syncthreads();   // SYNC_C: Rhp written; Ahp/Hs reads complete

        // ---- phase 3: r*h a-frags from Rhp
        v8s ra[2][2][2];
#pragma unroll
        for (int mf = 0; mf < 2; ++mf)
#pragma unroll
            for (int kc = 0; kc < 2; ++kc) {
                const int m = mf * 16 + lr;
                const int base = m * 128 + kc * 32 + hi * 8;
                const int sw = (m & 7) << 3;
                ra[mf][kc][0] = *(const v8s*)&Rhp[base ^ sw];
                ra[mf][kc][1] = *(const v8s*)&Rhp[(base + 64) ^ sw];
            }

        // ---- phase 4: z = xz (precomputed) + rh-part; overlap next-x z
        v4f accz[2];
#pragma unroll
        for (int mf = 0; mf < 2; ++mf) accz[mf] = xz[mf];

        {
            const int o = (w & 3) * 16 + lr;
            v8s wr_[2][2];
#pragma unroll
            for (int kc = 0; kc < 2; ++kc)
#pragma unroll
                for (int lev = 0; lev < 2; ++lev)
                    wr_[kc][lev] = *(const v8s*)&WZ[((size_t)t * 5 + 3 + lev) * 4096 + o * 64 + kc * 32 + hi * 8];
#pragma unroll
            for (int mf = 0; mf < 2; ++mf)
#pragma unroll
                for (int kc = 0; kc < 2; ++kc) {
                    v4f a = accz[mf];
                    a = __builtin_amdgcn_mfma_f32_16x16x32_bf16(ra[mf][kc][0], wr_[kc][0], a, 0, 0, 0);
                    a = __builtin_amdgcn_mfma_f32_16x16x32_bf16(ra[mf][kc][0], wr_[kc][1], a, 0, 0, 0);
                    a = __builtin_amdgcn_mfma_f32_16x16x32_bf16(ra[mf][kc][1], wr_[kc][0], a, 0, 0, 0);
                    accz[mf] = a;
                }
        }
        if (hasNext) xz_mfma(t + 1, xan, xzN);     // independent — fills stalls

        // ---- phase 5: epilogue (waves 4-7): hnew = u*z + (1-u)*h
        if (w >= 4) {
            const int o = (w & 3) * 16 + lr;
            const float bz = bzff[(size_t)t * 64 + o];
#pragma unroll
            for (int mf = 0; mf < 2; ++mf)
#pragma unroll
                for (int q = 0; q < 4; ++q) {
                    const int m = mf * 16 + hi * 4 + q;
                    const float z = ftanh(accz[mf][q] + bz);
                    const float u = u_[mf][q];
                    const float hn = u * z + (1.0f - u) * Hs[m][o];
                    Hs[m][o] = hn;
                    const unsigned short h = f2bf(hn);
                    const unsigned short l = f2bf(hn - bf2f(h));
                    const int sw = (m & 7) << 3;
                    Ahp[(m * 128 + o) ^ sw]      = h;
                    Ahp[(m * 128 + 64 + o) ^ sw] = l;
                    out[(((size_t)b * TT + t) * NN + n0 + m) * 64 + o] = hn;
                }
        }
        __syncthreads();   // SYNC_F: epilogue writes visible for next t

#pragma unroll
        for (int mf = 0; mf < 2; ++mf) { xru[mf] = xruN[mf]; xz[mf] = xzN[mf]; }
    }
}

// ---------------- fallback VALU GRU ----------------
__global__ __launch_bounds__(256) void gru_all(
    const float* __restrict__ y,    const float* __restrict__ wff,
    const float* __restrict__ bff,  const float* __restrict__ wzff,
    const float* __restrict__ bzff, float* __restrict__ out)
{
    __shared__ float Xs[64][36];
    __shared__ float Hs[64][36];
    __shared__ float Rs[64][36];
    __shared__ float Us[64][36];
    __shared__ float Ws[64][132];
    const int tid = threadIdx.x;
    const int mb  = blockIdx.x;
    const int b = mb >> 5, n0 = (mb & 31) * 32;
    const int rg = tid >> 5;
    const int og = tid & 31;

    for (int i = tid; i < 64 * 36; i += 256) (&Hs[0][0])[i] = 0.0f;

    for (int t = 0; t < TT; ++t) {
        {
            const float* xt = y + (((size_t)b * TT + t) * NN + n0) * DD;
            const int m = tid >> 3, c0 = (tid & 7) * 8;
            const float4 v0 = *(const float4*)&xt[m * DD + c0];
            const float4 v1 = *(const float4*)&xt[m * DD + c0 + 4];
            Xs[c0 + 0][m] = v0.x; Xs[c0 + 1][m] = v0.y;
            Xs[c0 + 2][m] = v0.z; Xs[c0 + 3][m] = v0.w;
            Xs[c0 + 4][m] = v1.x; Xs[c0 + 5][m] = v1.y;
            Xs[c0 + 6][m] = v1.z; Xs[c0 + 7][m] = v1.w;
        }
        float acc[4][4];
#pragma unroll
        for (int i = 0; i < 4; ++i)
#pragma unroll
            for (int j = 0; j < 4; ++j) acc[i][j] = 0.0f;

#pragma unroll
        for (int half = 0; half < 2; ++half) {
            __syncthreads();
#pragma unroll
            for (int p = 0; p < 8; ++p) {
                const int kk = (tid >> 5) + p * 8;
                const int o4 = (tid & 31) * 4;
                *(float4*)&Ws[kk][o4] =
                    *(const float4*)&wff[((size_t)t * 128 + half * 64 + kk) * 128 + o4];
            }
            __syncthreads();
            const float (*Asrc)[36] = half ? Hs : Xs;
#pragma unroll 4
            for (int kk = 0; kk < 64; ++kk) {
                const float4 av = *(const float4*)&Asrc[kk][rg * 4];
                const float4 wv = *(const float4*)&Ws[kk][og * 4];
                const float a0 = av.x, a1 = av.y, a2 = av.z, a3 = av.w;
                acc[0][0] = fmaf(a0, wv.x, acc[0][0]); acc[0][1] = fmaf(a0, wv.y, acc[0][1]);
                acc[0][2] = fmaf(a0, wv.z, acc[0][2]); acc[0][3] = fmaf(a0, wv.w, acc[0][3]);
                acc[1][0] = fmaf(a1, wv.x, acc[1][0]); acc[1][1] = fmaf(a1, wv.y, acc[1][1]);
                acc[1][2] = fmaf(a1, wv.z, acc[1][2]); acc[1][3] = fmaf(a1, wv.w, acc[1][3]);
                acc[2][0] = fmaf(a2, wv.x, acc[2][0]); acc[2][1] = fmaf(a2, wv.y, acc[2][1]);
                acc[2][2] = fmaf(a2, wv.z, acc[2][2]); acc[2][3] = fmaf(a2, wv.w, acc[2][3]);
                acc[3][0] = fmaf(a3, wv.x, acc[3][0]); acc[3][1] = fmaf(a3, wv.y, acc[3][1]);
                acc[3][2] = fmaf(a3, wv.z, acc[3][2]); acc[3][3] = fmaf(a3, wv.w, acc[3][3]);
            }
        }
        {
            const float4 bb4 = *(const float4*)&bff[(size_t)t * 128 + og * 4];
            float g[4][4];
#pragma unroll
            for (int i = 0; i < 4; ++i) {
                g[i][0] = sigmoidf_(acc[i][0] + bb4.x);
                g[i][1] = sigmoidf_(acc[i][1] + bb4.y);
                g[i][2] = sigmoidf_(acc[i][2] + bb4.z);
                g[i][3] = sigmoidf_(acc[i][3] + bb4.w);
            }
            if (og < 16) {
#pragma unroll
                for (int i = 0; i < 4; ++i)
#pragma unroll
                    for (int j = 0; j < 4; ++j) {
                        const int f = og * 4 + j, m = rg * 4 + i;
                        Rs[f][m] = g[i][j] * Hs[f][m];
                    }
            } else {
#pragma unroll
                for (int i = 0; i < 4; ++i)
#pragma unroll
                    for (int j = 0; j < 4; ++j)
                        Us[og * 4 + j - 64][rg * 4 + i] = g[i][j];
            }
        }
        float accz[4][2];
#pragma unroll
        for (int i = 0; i < 4; ++i) { accz[i][0] = 0.0f; accz[i][1] = 0.0f; }

#pragma unroll
        for (int half = 0; half < 2; ++half) {
            __syncthreads();
#pragma unroll
            for (int p = 0; p < 4; ++p) {
                const int kk = (tid >> 4) + p * 16;
                const int f4 = (tid & 15) * 4;
                *(float4*)&Ws[kk][f4] =
                    *(const float4*)&wzff[((size_t)t * 128 + half * 64 + kk) * 64 + f4];
            }
            __syncthreads();
            const float (*Asrc)[36] = half ? Rs : Xs;
#pragma unroll 4
            for (int kk = 0; kk < 64; ++kk) {
                const float4 av = *(const float4*)&Asrc[kk][rg * 4];
                const float2 wv = *(const float2*)&Ws[kk][og * 2];
                accz[0][0] = fmaf(av.x, wv.x, accz[0][0]); accz[0][1] = fmaf(av.x, wv.y, accz[0][1]);
                accz[1][0] = fmaf(av.y, wv.x, accz[1][0]); accz[1][1] = fmaf(av.y, wv.y, accz[1][1]);
                accz[2][0] = fmaf(av.z, wv.x, accz[2][0]); accz[2][1] = fmaf(av.z, wv.y, accz[2][1]);
                accz[3][0] = fmaf(av.w, wv.x, accz[3][0]); accz[3][1] = fmaf(av.w, wv.y, accz[3][1]);
            }
        }
        {
            const float2 bz = *(const float2*)&bzff[(size_t)t * 64 + og * 2];
            const int f0_ = og * 2;
#pragma unroll
            for (int i = 0; i < 4; ++i) {
                const int m = rg * 4 + i;
                const float z0 = tanhf(accz[i][0] + bz.x);
                const float z1 = tanhf(accz[i][1] + bz.y);
                const float u0 = Us[f0_][m],     u1 = Us[f0_ + 1][m];
                const float h0 = Hs[f0_][m],     h1 = Hs[f0_ + 1][m];
                const float hn0 = u0 * z0 + (1.0f - u0) * h0;
                const float hn1 = u1 * z1 + (1.0f - u1) * h1;
                Hs[f0_][m] = hn0; Hs[f0_ + 1][m] = hn1;
                *(float2*)&out[(((size_t)b * TT + t) * NN + n0 + m) * FF + f0_] =
                    make_float2(hn0, hn1);
            }
        }
        __syncthreads();
    }
}

extern "C" void kernel_launch(void* const* d_in, const int* in_sizes, int n_in,
                              void* d_out, int out_size, void* d_ws, size_t ws_size,
                              hipStream_t stream)
{
    const float* x        = (const float*)d_in[0];
    const float* A        = (const float*)d_in[1];
    const float* conv_w   = (const float*)d_in[2];
    const float* conv_b   = (const float*)d_in[3];
    const float* bn_gamma = (const float*)d_in[4];
    const float* bn_beta  = (const float*)d_in[5];
    const float* bn_mean  = (const float*)d_in[6];
    const float* bn_var   = (const float*)d_in[7];
    const float* gru_ff_w  = (const float*)d_in[8];
    const float* gru_ff_b  = (const float*)d_in[9];
    const float* gru_zff_w = (const float*)d_in[10];
    const float* gru_zff_b = (const float*)d_in[11];
    float* out = (float*)d_out;
    char* w = (char*)d_ws;

    const size_t szA_bf  = (size_t)NB * NN * NN * 2;    // 33,554,432 B
    const size_t szXT_bf = (size_t)NB * JT * NN * 2;    // 25,165,824 B
    const size_t needFast = 2 * szA_bf + 2 * szXT_bf + 2 * szXT_bf; // 167,772,160

    dim3 gconv(8, TT, NB);

    if (ws_size >= needFast) {
        unsigned short* Ah2 = (unsigned short*)(w);
        unsigned short* Al2 = (unsigned short*)(w + szA_bf);
        unsigned short* X1h = (unsigned short*)(w + 2 * szA_bf);
        unsigned short* X1l = (unsigned short*)(w + 2 * szA_bf + szXT_bf);
        char* slot = w + 2 * szA_bf + 2 * szXT_bf;      // [117.4M, 167.77M)
        unsigned short* xh = (unsigned short*)slot;
        unsigned short* xl = (unsigned short*)(slot + szXT_bf);
        float* X2T = (float*)slot;                       // after xh/xl dead
        // post-gemm phase: y + weight images over dead Ah/Al (67.1 MB)
        float* yb = (float*)w;                           // 50.33 MB
        unsigned short* WF = (unsigned short*)(w + 50331648);          // 983,040 B
        unsigned short* WZ = (unsigned short*)(w + 50331648 + 983040); // 491,520 B

        xsplitT<<<dim3(16, TT, NB), 256, 0, stream>>>(x, xh, xl);
        split_A<<<4096, 256, 0, stream>>>(A, Ah2, Al2);
        gemm_bf<true ><<<512, 256, 0, stream>>>(Ah2, Al2, xh,  xl,  X1h, X1l, nullptr);
        gemm_bf<false><<<512, 256, 0, stream>>>(Ah2, Al2, X1h, X1l, nullptr, nullptr, X2T);
        conv_bn_relu<true><<<gconv, 256, 0, stream>>>(x, X1h, X1l, X2T, nullptr, nullptr,
                                                      conv_w, conv_b, bn_gamma, bn_beta,
                                                      bn_mean, bn_var, yb);
        wprep3<<<TT, 256, 0, stream>>>(gru_ff_w, gru_zff_w, WF, WZ);
        gru10<<<512, 512, 0, stream>>>(yb, WF, WZ, gru_ff_b, gru_zff_b, out);
    } else {
        const size_t szX = (size_t)NB * NN * JT;        // floats
        float* X1 = (float*)w;
        float* X2 = X1 + szX;
        float* yb = X2 + szX;
        gemm_f32<true ><<<768, 256, 0, stream>>>(A, x,  X1);
        gemm_f32<false><<<768, 256, 0, stream>>>(A, X1, X2);
        conv_bn_relu<false><<<gconv, 256, 0, stream>>>(x, nullptr, nullptr, nullptr, X1, X2,
                                                       conv_w, conv_b, bn_gamma, bn_beta,
                                                       bn_mean, bn_var, yb);
        gru_all<<<512, 256, 0, stream>>>(yb, gru_ff_w, gru_ff_b,
                                         gru_zff_w, gru_zff_b, out);
    }
}

// Round 15
// 446.243 us; speedup vs baseline: 1.4285x; 1.4285x over previous
//
#include <hip/hip_runtime.h>
#include <cstdint>
#include <cstddef>

#define NB 16
#define TT 12
#define NN 1024
#define DD 64
#define FF 64
#define JT 768   // T*D

typedef __attribute__((ext_vector_type(8))) short v8s;
typedef __attribute__((ext_vector_type(4))) short v4s;
typedef __attribute__((ext_vector_type(4))) float v4f;

__device__ __forceinline__ float sigmoidf_(float v) { return 1.0f / (1.0f + expf(-v)); }
__device__ __forceinline__ float fsig(float v) {
    return __fdividef(1.0f, 1.0f + __expf(-v));
}
__device__ __forceinline__ float ftanh(float v) {
    v = fminf(fmaxf(v, -15.0f), 15.0f);
    const float e = __expf(2.0f * v);
    return __fdividef(e - 1.0f, e + 1.0f);
}

__device__ __forceinline__ float bf2f(unsigned short h) {
    union { unsigned int u; float f; } x; x.u = ((unsigned int)h) << 16; return x.f;
}
__device__ __forceinline__ unsigned short f2bf(float f) {
    union { float f; unsigned int u; } x; x.f = f;
    return (unsigned short)((x.u + 0x7fffu + ((x.u >> 16) & 1u)) >> 16);
}

__device__ __forceinline__ void gload16(const void* g, void* lds) {
    __builtin_amdgcn_global_load_lds(
        (const __attribute__((address_space(1))) void*)g,
        (__attribute__((address_space(3))) void*)lds, 16, 0, 0);
}

// ---------------- split A (fp32 row-major) -> Ah, Al bf16 row-major ----------
__global__ __launch_bounds__(256) void split_A(
    const float* __restrict__ A, unsigned short* __restrict__ Ah,
    unsigned short* __restrict__ Al)
{
    const size_t i0 = ((size_t)blockIdx.x * 256 + threadIdx.x) * 16;
    float v[16];
#pragma unroll
    for (int s = 0; s < 4; ++s)
        *(float4*)&v[s * 4] = *(const float4*)&A[i0 + s * 4];
    v8s h0, h1, l0, l1;
#pragma unroll
    for (int q = 0; q < 8; ++q) {
        unsigned short h = f2bf(v[q]);
        h0[q] = (short)h; l0[q] = (short)f2bf(v[q] - bf2f(h));
    }
#pragma unroll
    for (int q = 0; q < 8; ++q) {
        unsigned short h = f2bf(v[8 + q]);
        h1[q] = (short)h; l1[q] = (short)f2bf(v[8 + q] - bf2f(h));
    }
    *(v8s*)&Ah[i0] = h0; *(v8s*)&Ah[i0 + 8] = h1;
    *(v8s*)&Al[i0] = l0; *(v8s*)&Al[i0 + 8] = l1;
}

// ------ split+transpose x (B,T,N,D) fp32 -> xTh,xTl (B, 768, 1024) bf16 ------
__global__ __launch_bounds__(256) void xsplitT(
    const float* __restrict__ x, unsigned short* __restrict__ Th,
    unsigned short* __restrict__ Tl)
{
    __shared__ float tile[64][68];
    const int v0 = blockIdx.x * 64, t = blockIdx.y, b = blockIdx.z;
    const int tid = threadIdx.x;
    {
        const int r = tid >> 2, q = (tid & 3) * 16;
#pragma unroll
        for (int s = 0; s < 4; ++s) {
            const float4 w = *(const float4*)&x[(((size_t)b * TT + t) * NN + v0 + r) * DD + q + s * 4];
            tile[r][q + s * 4 + 0] = w.x; tile[r][q + s * 4 + 1] = w.y;
            tile[r][q + s * 4 + 2] = w.z; tile[r][q + s * 4 + 3] = w.w;
        }
    }
    __syncthreads();
    {
        const int d = tid >> 2, vc = (tid & 3) * 16;
        const size_t base = ((size_t)b * JT + t * 64 + d) * 1024 + v0 + vc;
        v8s h0, h1, l0, l1;
#pragma unroll
        for (int s = 0; s < 8; ++s) {
            const float f = tile[vc + s][d];
            unsigned short h = f2bf(f);
            h0[s] = (short)h; l0[s] = (short)f2bf(f - bf2f(h));
        }
#pragma unroll
        for (int s = 0; s < 8; ++s) {
            const float f = tile[vc + 8 + s][d];
            unsigned short h = f2bf(f);
            h1[s] = (short)h; l1[s] = (short)f2bf(f - bf2f(h));
        }
        *(v8s*)&Th[base] = h0; *(v8s*)&Th[base + 8] = h1;
        *(v8s*)&Tl[base] = l0; *(v8s*)&Tl[base + 8] = l1;
    }
}

// -------- bf16 split-2 MFMA GEMM: C[b][n][m] = sum_k A[b][m][k] * B[b][n][k] --
// 128m x 192n tiles -> grid 512 = exactly 2 blocks/CU, no tail.
// 3 products: AhBh + AhBl + AlBh (al*bl dropped: measured cost <=1e-3 absmax).
template<bool PAIROUT>
__global__ __launch_bounds__(256, 2) void gemm_bf(
    const unsigned short* __restrict__ Ah, const unsigned short* __restrict__ Al,
    const unsigned short* __restrict__ Bh, const unsigned short* __restrict__ Bl,
    unsigned short* __restrict__ Ch, unsigned short* __restrict__ Cl,
    float* __restrict__ Cf)
{
    __shared__ unsigned short LA[2][2][4096];   // [buf][hi/lo][128m x 32k]
    __shared__ unsigned short LB[2][2][6144];   // [buf][hi/lo][192n x 32k]

    const int wg = blockIdx.x;
    const int nlin = (wg & 7) * 64 + (wg >> 3);
    const int b  = nlin >> 5;
    const int rr = nlin & 31;
    const int m0 = (rr >> 2) * 128, n0 = (rr & 3) * 192;

    const int tid = threadIdx.x, lane = tid & 63, wid = tid >> 6;
    const int lr = lane & 15, hi = lane >> 4;
    const int wr = wid >> 1, wc = wid & 1;

    auto stage = [&](int buf, int kt) {
        const int rA = lane >> 2, kc = (lane & 3) * 8;
#pragma unroll
        for (int p = 0; p < 2; ++p) {
            const int c = wid * 2 + p;
            const size_t ga = ((size_t)b * 1024 + m0 + c * 16 + rA) * 1024 + kt * 32 + kc;
            gload16(Ah + ga, &LA[buf][0][c * 512]);
            gload16(Al + ga, &LA[buf][1][c * 512]);
        }
#pragma unroll
        for (int p = 0; p < 3; ++p) {
            const int c = wid * 3 + p;
            const size_t gb = ((size_t)b * JT + n0 + c * 16 + rA) * 1024 + kt * 32 + kc;
            gload16(Bh + gb, &LB[buf][0][c * 512]);
            gload16(Bl + gb, &LB[buf][1][c * 512]);
        }
    };

    v4f acc[4][6];
#pragma unroll
    for (int i = 0; i < 4; ++i)
#pragma unroll
        for (int j = 0; j < 6; ++j) acc[i][j] = (v4f){0.f, 0.f, 0.f, 0.f};

    stage(0, 0);
    __syncthreads();
    int cur = 0;
    for (int kt = 0; kt < 32; ++kt) {
        if (kt + 1 < 32) stage(cur ^ 1, kt + 1);
        v8s ah[4], al[4], bh[6], bl[6];
#pragma unroll
        for (int f = 0; f < 4; ++f) {
            const int m = wr * 64 + f * 16 + lr;
            ah[f] = *(const v8s*)&LA[cur][0][m * 32 + hi * 8];
            al[f] = *(const v8s*)&LA[cur][1][m * 32 + hi * 8];
        }
#pragma unroll
        for (int f = 0; f < 6; ++f) {
            const int n = wc * 96 + f * 16 + lr;
            bh[f] = *(const v8s*)&LB[cur][0][n * 32 + hi * 8];
            bl[f] = *(const v8s*)&LB[cur][1][n * 32 + hi * 8];
        }
#pragma unroll
        for (int fi = 0; fi < 4; ++fi)
#pragma unroll
            for (int fj = 0; fj < 6; ++fj) {
                acc[fi][fj] = __builtin_amdgcn_mfma_f32_16x16x32_bf16(ah[fi], bh[fj], acc[fi][fj], 0, 0, 0);
                acc[fi][fj] = __builtin_amdgcn_mfma_f32_16x16x32_bf16(ah[fi], bl[fj], acc[fi][fj], 0, 0, 0);
                acc[fi][fj] = __builtin_amdgcn_mfma_f32_16x16x32_bf16(al[fi], bh[fj], acc[fi][fj], 0, 0, 0);
            }
        __syncthreads();
        cur ^= 1;
    }

#pragma unroll
    for (int fi = 0; fi < 4; ++fi)
#pragma unroll
        for (int fj = 0; fj < 6; ++fj) {
            const int n  = n0 + wc * 96 + fj * 16 + lr;
            const int mb = m0 + wr * 64 + fi * 16 + hi * 4;
            const size_t o = ((size_t)b * JT + n) * 1024 + mb;
            if (PAIROUT) {
                v4s vh, vl;
#pragma unroll
                for (int r = 0; r < 4; ++r) {
                    const float v = acc[fi][fj][r];
                    const unsigned short h = f2bf(v);
                    vh[r] = (short)h; vl[r] = (short)f2bf(v - bf2f(h));
                }
                *(v4s*)&Ch[o] = vh;
                *(v4s*)&Cl[o] = vl;
            } else {
                float4 v = {acc[fi][fj][0], acc[fi][fj][1], acc[fi][fj][2], acc[fi][fj][3]};
                *(float4*)&Cf[o] = v;
            }
        }
}

// -------------- fallback fp32 GEMM --------
template<bool XFROMX>
__global__ __launch_bounds__(256, 4) void gemm_f32(
    const float* __restrict__ Aop, const float* __restrict__ Xin,
    float* __restrict__ Xout)
{
    __shared__ float As[2][16 * 132];
    __shared__ float Bs[2][16 * 128];
    const int wg  = blockIdx.x;
    const int nlin = (wg & 7) * 96 + (wg >> 3);
    const int b  = nlin / 48;
    const int rr = nlin % 48;
    const int rb = rr / 6, cb = rr % 6;
    const int w0 = rb * 128, j0 = cb * 128;
    const int tid = threadIdx.x;
    const int rg = tid >> 4, cg = tid & 15;
    const int row0 = rg * 8;

    auto stage = [&](int buf, int kt) {
        const float* Ab = Aop + (size_t)b * NN * NN;
#pragma unroll
        for (int p = 0; p < 2; ++p) {
            const int c  = tid + p * 256;
            const int w  = c >> 2;
            const int k4 = (c & 3) * 4;
            const float4 v = *(const float4*)&Ab[(size_t)(w0 + w) * NN + kt * 16 + k4];
            As[buf][(k4 + 0) * 132 + w] = v.x;
            As[buf][(k4 + 1) * 132 + w] = v.y;
            As[buf][(k4 + 2) * 132 + w] = v.z;
            As[buf][(k4 + 3) * 132 + w] = v.w;
        }
#pragma unroll
        for (int p = 0; p < 2; ++p) {
            const int c = tid + p * 256;
            const int k = c >> 5;
            const int j = (c & 31) * 4;
            float4 v;
            if (XFROMX) {
                const int t = cb * 2 + (j >> 6);
                const int d = j & 63;
                v = *(const float4*)&Xin[(((size_t)b * TT + t) * NN + (size_t)kt * 16 + k) * DD + d];
            } else {
                v = *(const float4*)&Xin[((size_t)b * NN + (size_t)kt * 16 + k) * JT + j0 + j];
            }
            *(float4*)&Bs[buf][k * 128 + j] = v;
        }
    };

    float acc[8][8];
#pragma unroll
    for (int i = 0; i < 8; ++i)
#pragma unroll
        for (int j = 0; j < 8; ++j) acc[i][j] = 0.0f;

    stage(0, 0);
    __syncthreads();
    int cur = 0;
    for (int kt = 0; kt < 64; ++kt) {
        if (kt + 1 < 64) stage(cur ^ 1, kt + 1);
#pragma unroll
        for (int k = 0; k < 16; ++k) {
            float a[8], bb[8];
            *(float4*)&a[0]  = *(const float4*)&As[cur][k * 132 + row0];
            *(float4*)&a[4]  = *(const float4*)&As[cur][k * 132 + row0 + 4];
            *(float4*)&bb[0] = *(const float4*)&Bs[cur][k * 128 + cg * 4];
            *(float4*)&bb[4] = *(const float4*)&Bs[cur][k * 128 + 64 + cg * 4];
#pragma unroll
            for (int i = 0; i < 8; ++i)
#pragma unroll
                for (int j = 0; j < 8; ++j)
                    acc[i][j] = fmaf(a[i], bb[j], acc[i][j]);
        }
        __syncthreads();
        cur ^= 1;
    }
#pragma unroll
    for (int i = 0; i < 8; ++i) {
        float4 v0 = {acc[i][0], acc[i][1], acc[i][2], acc[i][3]};
        float4 v1 = {acc[i][4], acc[i][5], acc[i][6], acc[i][7]};
        float* dst = Xout + ((size_t)b * NN + w0 + row0 + i) * JT + j0;
        *(float4*)&dst[cg * 4]      = v0;
        *(float4*)&dst[64 + cg * 4] = v1;
    }
}

// ---------------- conv (BTN x 192 @ 192 x 64) + BN + ReLU -> fp32 y ---------
template<bool PAIRS>
__global__ __launch_bounds__(256) void conv_bn_relu(
    const float* __restrict__ x,
    const unsigned short* __restrict__ X1h, const unsigned short* __restrict__ X1l,
    const float* __restrict__ X2T,
    const float* __restrict__ X1f, const float* __restrict__ X2f,
    const float* __restrict__ W,
    const float* __restrict__ convb, const float* __restrict__ gamma,
    const float* __restrict__ beta,  const float* __restrict__ mean,
    const float* __restrict__ var,   float* __restrict__ y)
{
    __shared__ float As[64][132];
    __shared__ float Ws[64][68];
    const int nb = blockIdx.x, t = blockIdx.y, b = blockIdx.z;
    const int n0 = nb * 128;
    const int tid = threadIdx.x;
    const int rg = tid >> 4, cg = tid & 15;
    const int row0 = rg * 8, f0 = cg * 4;

    float acc[8][4];
#pragma unroll
    for (int i = 0; i < 8; ++i)
#pragma unroll
        for (int j = 0; j < 4; ++j) acc[i][j] = 0.0f;

    for (int kt = 0; kt < 3; ++kt) {
        __syncthreads();
        if (kt == 0) {
            const float* src = x + (((size_t)b * TT + t) * NN + n0) * DD;
#pragma unroll
            for (int p = 0; p < 8; ++p) {
                const int row = (tid >> 4) + p * 16;
                const int c4  = (tid & 15) * 4;
                const float4 v = *(const float4*)&src[(size_t)row * DD + c4];
                As[c4 + 0][row] = v.x; As[c4 + 1][row] = v.y;
                As[c4 + 2][row] = v.z; As[c4 + 3][row] = v.w;
            }
        } else if (PAIRS) {
            if (kt == 1) {
#pragma unroll
                for (int p = 0; p < 4; ++p) {
                    const int pos = p * 256 + tid;
                    const int c = pos >> 4, rw = (pos & 15) * 8;
                    const size_t o = ((size_t)b * JT + t * 64 + c) * 1024 + n0 + rw;
                    const v8s hv = *(const v8s*)&X1h[o];
                    const v8s lv = *(const v8s*)&X1l[o];
#pragma unroll
                    for (int q = 0; q < 8; ++q)
                        As[c][rw + q] = bf2f((unsigned short)hv[q]) + bf2f((unsigned short)lv[q]);
                }
            } else {
#pragma unroll
                for (int p = 0; p < 8; ++p) {
                    const int pos = p * 256 + tid;
                    const int c = pos >> 5, rw = (pos & 31) * 4;
                    const float4 v = *(const float4*)&X2T[((size_t)b * JT + t * 64 + c) * 1024 + n0 + rw];
                    As[c][rw + 0] = v.x; As[c][rw + 1] = v.y;
                    As[c][rw + 2] = v.z; As[c][rw + 3] = v.w;
                }
            }
        } else {
            const float* src = ((kt == 1) ? X1f : X2f) + ((size_t)b * NN + n0) * JT + t * DD;
#pragma unroll
            for (int p = 0; p < 8; ++p) {
                const int row = (tid >> 4) + p * 16;
                const int c4  = (tid & 15) * 4;
                const float4 v = *(const float4*)&src[(size_t)row * JT + c4];
                As[c4 + 0][row] = v.x; As[c4 + 1][row] = v.y;
                As[c4 + 2][row] = v.z; As[c4 + 3][row] = v.w;
            }
        }
#pragma unroll
        for (int p = 0; p < 4; ++p) {
            const int f  = (tid >> 4) + p * 16;
            const int c4 = (tid & 15) * 4;
            const float4 v = *(const float4*)&W[f * 192 + kt * 64 + c4];
            Ws[c4 + 0][f] = v.x; Ws[c4 + 1][f] = v.y;
            Ws[c4 + 2][f] = v.z; Ws[c4 + 3][f] = v.w;
        }
        __syncthreads();
#pragma unroll
        for (int k = 0; k < 64; ++k) {
            float a[8], w[4];
            *(float4*)&a[0] = *(const float4*)&As[k][row0];
            *(float4*)&a[4] = *(const float4*)&As[k][row0 + 4];
            *(float4*)&w[0] = *(const float4*)&Ws[k][f0];
#pragma unroll
            for (int i = 0; i < 8; ++i)
#pragma unroll
                for (int j = 0; j < 4; ++j)
                    acc[i][j] = fmaf(a[i], w[j], acc[i][j]);
        }
    }
    float s[4], off[4];
#pragma unroll
    for (int j = 0; j < 4; ++j) {
        const int f = f0 + j;
        const float sc = gamma[f] / sqrtf(var[f] + 1e-5f);
        s[j]   = sc;
        off[j] = (convb[f] - mean[f]) * sc + beta[f];
    }
#pragma unroll
    for (int i = 0; i < 8; ++i) {
        float4 v;
        v.x = fmaxf(acc[i][0] * s[0] + off[0], 0.0f);
        v.y = fmaxf(acc[i][1] * s[1] + off[1], 0.0f);
        v.z = fmaxf(acc[i][2] * s[2] + off[2], 0.0f);
        v.w = fmaxf(acc[i][3] * s[3] + off[3], 0.0f);
        *(float4*)&y[(((size_t)b * TT + t) * NN + n0 + row0 + i) * FF + f0] = v;
    }
}

// ------- GRU weight prep: 5 bf16 planes per t for ru (WF) and z (WZ) --------
__global__ __launch_bounds__(256) void wprep3(
    const float* __restrict__ wff, const float* __restrict__ wzff,
    unsigned short* __restrict__ WF, unsigned short* __restrict__ WZ)
{
    const int t = blockIdx.x;
    unsigned short* F = WF + (size_t)t * 40960;
    for (int e = threadIdx.x; e < 8192; e += 256) {
        const int o = e >> 6, k = e & 63;
        const float vx = wff[((size_t)t * 128 + k) * 128 + o];
        const unsigned short xh = f2bf(vx);
        const float r1 = vx - bf2f(xh);
        const unsigned short xm = f2bf(r1);
        const unsigned short xl = f2bf(r1 - bf2f(xm));
        F[0 * 8192 + o * 64 + k] = xh;
        F[1 * 8192 + o * 64 + k] = xm;
        F[2 * 8192 + o * 64 + k] = xl;
        const float vh = wff[((size_t)t * 128 + 64 + k) * 128 + o];
        const unsigned short hh = f2bf(vh);
        const unsigned short hl = f2bf(vh - bf2f(hh));
        F[3 * 8192 + o * 64 + k] = hh;
        F[4 * 8192 + o * 64 + k] = hl;
    }
    unsigned short* Z = WZ + (size_t)t * 20480;
    for (int e = threadIdx.x; e < 4096; e += 256) {
        const int o = e >> 6, k = e & 63;
        const float vx = wzff[((size_t)t * 128 + k) * 64 + o];
        const unsigned short xh = f2bf(vx);
        const float r1 = vx - bf2f(xh);
        const unsigned short xm = f2bf(r1);
        const unsigned short xl = f2bf(r1 - bf2f(xm));
        Z[0 * 4096 + o * 64 + k] = xh;
        Z[1 * 4096 + o * 64 + k] = xm;
        Z[2 * 4096 + o * 64 + k] = xl;
        const float vr = wzff[((size_t)t * 128 + 64 + k) * 64 + o];
        const unsigned short rh = f2bf(vr);
        const unsigned short rl = f2bf(vr - bf2f(rh));
        Z[3 * 4096 + o * 64 + k] = rh;
        Z[4 * 4096 + o * 64 + k] = rl;
    }
}

// ------ fused GRU v7 (proven 167 us): 32-row/512-block, 2 barriers/step,
// fast transcendentals, x-part MFMAs for t+1 pipelined into step t. ------
__global__ __launch_bounds__(256, 2) void gru7(
    const float* __restrict__ y,
    const unsigned short* __restrict__ WF, const unsigned short* __restrict__ WZ,
    const float* __restrict__ bff, const float* __restrict__ bzff,
    float* __restrict__ out)
{
    __shared__ unsigned short Ahp[4096];   // h pairs   [m 32][{h[64]|l[64]}] ^ ((m&7)<<3)
    __shared__ unsigned short Rhp[4096];   // r*h pairs same layout
    __shared__ float Hs[32][68];           // fp32 h state

    const int tid = threadIdx.x, lane = tid & 63, w = tid >> 6;
    const int lr = lane & 15, hi = lane >> 4;
    const int b = blockIdx.x >> 5, n0 = (blockIdx.x & 31) * 32;

    for (int i = tid; i < 4096; i += 256) { Ahp[i] = 0; Rhp[i] = 0; }
    for (int i = tid; i < 32 * 68; i += 256) (&Hs[0][0])[i] = 0.0f;
    __syncthreads();

    auto loadx = [&](int t, v8s xa[2][2][3]) {
        const float* yb = y + (((size_t)b * TT + t) * NN + n0) * 64;
#pragma unroll
        for (int mf = 0; mf < 2; ++mf)
#pragma unroll
            for (int kc = 0; kc < 2; ++kc) {
                const int m = mf * 16 + lr;
                float xv[8];
                *(float4*)&xv[0] = *(const float4*)&yb[m * 64 + kc * 32 + hi * 8];
                *(float4*)&xv[4] = *(const float4*)&yb[m * 64 + kc * 32 + hi * 8 + 4];
                v8s h3, m3, l3;
#pragma unroll
                for (int q = 0; q < 8; ++q) {
                    const float v = xv[q];
                    const unsigned short hh = f2bf(v);
                    const float r1 = v - bf2f(hh);
                    const unsigned short mm = f2bf(r1);
                    const unsigned short ll = f2bf(r1 - bf2f(mm));
                    h3[q] = (short)hh; m3[q] = (short)mm; l3[q] = (short)ll;
                }
                xa[mf][kc][0] = h3; xa[mf][kc][1] = m3; xa[mf][kc][2] = l3;
            }
    };
    auto xru_mfma = [&](int t, const v8s xa[2][2][3], v4f xacc[2][2]) {
#pragma unroll
        for (int of = 0; of < 2; ++of) {
            const int o = (2 * w + of) * 16 + lr;
            v8s wx[2][3];
#pragma unroll
            for (int kc = 0; kc < 2; ++kc)
#pragma unroll
                for (int lev = 0; lev < 3; ++lev)
                    wx[kc][lev] = *(const v8s*)&WF[((size_t)t * 5 + lev) * 8192 + o * 64 + kc * 32 + hi * 8];
#pragma unroll
            for (int mf = 0; mf < 2; ++mf)
#pragma unroll
                for (int kc = 0; kc < 2; ++kc) {
                    v4f a = xacc[of][mf];
                    a = __builtin_amdgcn_mfma_f32_16x16x32_bf16(xa[mf][kc][0], wx[kc][0], a, 0, 0, 0);
                    a = __builtin_amdgcn_mfma_f32_16x16x32_bf16(xa[mf][kc][0], wx[kc][1], a, 0, 0, 0);
                    a = __builtin_amdgcn_mfma_f32_16x16x32_bf16(xa[mf][kc][1], wx[kc][0], a, 0, 0, 0);
                    a = __builtin_amdgcn_mfma_f32_16x16x32_bf16(xa[mf][kc][0], wx[kc][2], a, 0, 0, 0);
                    a = __builtin_amdgcn_mfma_f32_16x16x32_bf16(xa[mf][kc][1], wx[kc][1], a, 0, 0, 0);
                    a = __builtin_amdgcn_mfma_f32_16x16x32_bf16(xa[mf][kc][2], wx[kc][0], a, 0, 0, 0);
                    xacc[of][mf] = a;
                }
        }
    };
    auto xz_mfma = [&](int t, const v8s xa[2][2][3], v4f xacc[2][2]) {
#pragma unroll
        for (int of = 0; of < 2; ++of) {
            const int o = (w & 1) * 32 + of * 16 + lr;
            v8s wx[2][3];
#pragma unroll
            for (int kc = 0; kc < 2; ++kc)
#pragma unroll
                for (int lev = 0; lev < 3; ++lev)
                    wx[kc][lev] = *(const v8s*)&WZ[((size_t)t * 5 + lev) * 4096 + o * 64 + kc * 32 + hi * 8];
#pragma unroll
            for (int mf = 0; mf < 2; ++mf)
#pragma unroll
                for (int kc = 0; kc < 2; ++kc) {
                    v4f a = xacc[of][mf];
                    a = __builtin_amdgcn_mfma_f32_16x16x32_bf16(xa[mf][kc][0], wx[kc][0], a, 0, 0, 0);
                    a = __builtin_amdgcn_mfma_f32_16x16x32_bf16(xa[mf][kc][0], wx[kc][1], a, 0, 0, 0);
                    a = __builtin_amdgcn_mfma_f32_16x16x32_bf16(xa[mf][kc][1], wx[kc][0], a, 0, 0, 0);
                    a = __builtin_amdgcn_mfma_f32_16x16x32_bf16(xa[mf][kc][0], wx[kc][2], a, 0, 0, 0);
                    a = __builtin_amdgcn_mfma_f32_16x16x32_bf16(xa[mf][kc][1], wx[kc][1], a, 0, 0, 0);
                    a = __builtin_amdgcn_mfma_f32_16x16x32_bf16(xa[mf][kc][2], wx[kc][0], a, 0, 0, 0);
                    xacc[of][mf] = a;
                }
        }
    };

    // prologue: x contributions for t=0
    v4f xru[2][2], xz[2][2];
#pragma unroll
    for (int of = 0; of < 2; ++of)
#pragma unroll
        for (int mf = 0; mf < 2; ++mf) {
            xru[of][mf] = (v4f){0.f, 0.f, 0.f, 0.f};
            xz[of][mf]  = (v4f){0.f, 0.f, 0.f, 0.f};
        }
    {
        v8s xa0[2][2][3];
        loadx(0, xa0);
        xru_mfma(0, xa0, xru);
        xz_mfma(0, xa0, xz);
    }

    for (int t = 0; t < TT; ++t) {
        const int hasNext = (t + 1 < TT);
        // ---- phase 0: h a-frags from Ahp (ordered before epilogue by SYNC_C)
        v8s ha[2][2][2];
#pragma unroll
        for (int mf = 0; mf < 2; ++mf)
#pragma unroll
            for (int kc = 0; kc < 2; ++kc) {
                const int m = mf * 16 + lr;
                const int base = m * 128 + kc * 32 + hi * 8;
                const int sw = (m & 7) << 3;
                ha[mf][kc][0] = *(const v8s*)&Ahp[base ^ sw];
                ha[mf][kc][1] = *(const v8s*)&Ahp[(base + 64) ^ sw];
            }

        // ---- phase 1: ru = xru (precomputed) + h-part; overlap next-x load + ru
        v4f acc[2][2];
#pragma unroll
        for (int of = 0; of < 2; ++of)
#pragma unroll
            for (int mf = 0; mf < 2; ++mf) acc[of][mf] = xru[of][mf];

        v8s xan[2][2][3];
        v4f xruN[2][2], xzN[2][2];
#pragma unroll
        for (int of = 0; of < 2; ++of)
#pragma unroll
            for (int mf = 0; mf < 2; ++mf) {
                xruN[of][mf] = (v4f){0.f, 0.f, 0.f, 0.f};
                xzN[of][mf]  = (v4f){0.f, 0.f, 0.f, 0.f};
            }
        if (hasNext) loadx(t + 1, xan);

#pragma unroll
        for (int of = 0; of < 2; ++of) {
            const int o = (2 * w + of) * 16 + lr;
            v8s wh_[2][2];
#pragma unroll
            for (int kc = 0; kc < 2; ++kc)
#pragma unroll
                for (int lev = 0; lev < 2; ++lev)
                    wh_[kc][lev] = *(const v8s*)&WF[((size_t)t * 5 + 3 + lev) * 8192 + o * 64 + kc * 32 + hi * 8];
#pragma unroll
            for (int mf = 0; mf < 2; ++mf)
#pragma unroll
                for (int kc = 0; kc < 2; ++kc) {
                    v4f a = acc[of][mf];
                    a = __builtin_amdgcn_mfma_f32_16x16x32_bf16(ha[mf][kc][0], wh_[kc][0], a, 0, 0, 0);
                    a = __builtin_amdgcn_mfma_f32_16x16x32_bf16(ha[mf][kc][0], wh_[kc][1], a, 0, 0, 0);
                    a = __builtin_amdgcn_mfma_f32_16x16x32_bf16(ha[mf][kc][1], wh_[kc][0], a, 0, 0, 0);
                    acc[of][mf] = a;
                }
        }
        if (hasNext) xru_mfma(t + 1, xan, xruN);   // independent — fills stalls

        // ---- phase 2: activations — waves 0-1 write Rhp; waves 2-3 keep u
        float u_[2][2][4];
#pragma unroll
        for (int of = 0; of < 2; ++of) {
            const int o = (2 * w + of) * 16 + lr;
            const float bv = bff[(size_t)t * 128 + o];
#pragma unroll
            for (int mf = 0; mf < 2; ++mf)
#pragma unroll
                for (int q = 0; q < 4; ++q) {
                    const float g = fsig(acc[of][mf][q] + bv);
                    if (w < 2) {
                        const int m = mf * 16 + hi * 4 + q;
                        const float rh = g * Hs[m][o];
                        const unsigned short h = f2bf(rh);
                        const unsigned short l = f2bf(rh - bf2f(h));
                        const int sw = (m & 7) << 3;
                        Rhp[(m * 128 + o) ^ sw]      = h;
                        Rhp[(m * 128 + 64 + o) ^ sw] = l;
                    } else {
                        u_[of][mf][q] = g;
                    }
                }
        }
        __syncthreads();   // SYNC_C: Rhp written; Ahp/Hs reads complete

        // ---- phase 3: r*h a-frags from Rhp
        v8s ra[2][2][2];
#pragma unroll
        for (int mf = 0; mf < 2; ++mf)
#pragma unroll
            for (int kc = 0; kc < 2; ++kc) {
                const int m = mf * 16 + lr;
                const int base = m * 128 + kc * 32 + hi * 8;
                const int sw = (m & 7) << 3;
                ra[mf][kc][0] = *(const v8s*)&Rhp[base ^ sw];
                ra[mf][kc][1] = *(const v8s*)&Rhp[(base + 64) ^ sw];
            }

        // ---- phase 4: z = xz (precomputed) + rh-part; overlap next-x z
        v4f accz[2][2];
#pragma unroll
        for (int of = 0; of < 2; ++of)
#pragma unroll
            for (int mf = 0; mf < 2; ++mf) accz[of][mf] = xz[of][mf];

#pragma unroll
        for (int of = 0; of < 2; ++of) {
            const int o = (w & 1) * 32 + of * 16 + lr;
            v8s wr_[2][2];
#pragma unroll
            for (int kc = 0; kc < 2; ++kc)
#pragma unroll
                for (int lev = 0; lev < 2; ++lev)
                    wr_[kc][lev] = *(const v8s*)&WZ[((size_t)t * 5 + 3 + lev) * 4096 + o * 64 + kc * 32 + hi * 8];
#pragma unroll
            for (int mf = 0; mf < 2; ++mf)
#pragma unroll
                for (int kc = 0; kc < 2; ++kc) {
                    v4f a = accz[of][mf];
                    a = __builtin_amdgcn_mfma_f32_16x16x32_bf16(ra[mf][kc][0], wr_[kc][0], a, 0, 0, 0);
                    a = __builtin_amdgcn_mfma_f32_16x16x32_bf16(ra[mf][kc][0], wr_[kc][1], a, 0, 0, 0);
                    a = __builtin_amdgcn_mfma_f32_16x16x32_bf16(ra[mf][kc][1], wr_[kc][0], a, 0, 0, 0);
                    accz[of][mf] = a;
                }
        }
        if (hasNext) xz_mfma(t + 1, xan, xzN);     // independent — fills stalls

        // ---- phase 5: epilogue (waves 2-3): hnew = u*z + (1-u)*h
        if (w >= 2) {
#pragma unroll
            for (int of = 0; of < 2; ++of) {
                const int o = (w & 1) * 32 + of * 16 + lr;
                const float bz = bzff[(size_t)t * 64 + o];
#pragma unroll
                for (int mf = 0; mf < 2; ++mf)
#pragma unroll
                    for (int q = 0; q < 4; ++q) {
                        const int m = mf * 16 + hi * 4 + q;
                        const float z = ftanh(accz[of][mf][q] + bz);
                        const float u = u_[of][mf][q];
                        const float hn = u * z + (1.0f - u) * Hs[m][o];
                        Hs[m][o] = hn;
                        const unsigned short h = f2bf(hn);
                        const unsigned short l = f2bf(hn - bf2f(h));
                        const int sw = (m & 7) << 3;
                        Ahp[(m * 128 + o) ^ sw]      = h;
                        Ahp[(m * 128 + 64 + o) ^ sw] = l;
                        out[(((size_t)b * TT + t) * NN + n0 + m) * 64 + o] = hn;
                    }
            }
        }
        __syncthreads();   // SYNC_F: epilogue writes visible for next t

#pragma unroll
        for (int of = 0; of < 2; ++of)
#pragma unroll
            for (int mf = 0; mf < 2; ++mf) {
                xru[of][mf] = xruN[of][mf];
                xz[of][mf]  = xzN[of][mf];
            }
    }
}

// ---------------- fallback VALU GRU ----------------
__global__ __launch_bounds__(256) void gru_all(
    const float* __restrict__ y,    const float* __restrict__ wff,
    const float* __restrict__ bff,  const float* __restrict__ wzff,
    const float* __restrict__ bzff, float* __restrict__ out)
{
    __shared__ float Xs[64][36];
    __shared__ float Hs[64][36];
    __shared__ float Rs[64][36];
    __shared__ float Us[64][36];
    __shared__ float Ws[64][132];
    const int tid = threadIdx.x;
    const int mb  = blockIdx.x;
    const int b = mb >> 5, n0 = (mb & 31) * 32;
    const int rg = tid >> 5;
    const int og = tid & 31;

    for (int i = tid; i < 64 * 36; i += 256) (&Hs[0][0])[i] = 0.0f;

    for (int t = 0; t < TT; ++t) {
        {
            const float* xt = y + (((size_t)b * TT + t) * NN + n0) * DD;
            const int m = tid >> 3, c0 = (tid & 7) * 8;
            const float4 v0 = *(const float4*)&xt[m * DD + c0];
            const float4 v1 = *(const float4*)&xt[m * DD + c0 + 4];
            Xs[c0 + 0][m] = v0.x; Xs[c0 + 1][m] = v0.y;
            Xs[c0 + 2][m] = v0.z; Xs[c0 + 3][m] = v0.w;
            Xs[c0 + 4][m] = v1.x; Xs[c0 + 5][m] = v1.y;
            Xs[c0 + 6][m] = v1.z; Xs[c0 + 7][m] = v1.w;
        }
        float acc[4][4];
#pragma unroll
        for (int i = 0; i < 4; ++i)
#pragma unroll
            for (int j = 0; j < 4; ++j) acc[i][j] = 0.0f;

#pragma unroll
        for (int half = 0; half < 2; ++half) {
            __syncthreads();
#pragma unroll
            for (int p = 0; p < 8; ++p) {
                const int kk = (tid >> 5) + p * 8;
                const int o4 = (tid & 31) * 4;
                *(float4*)&Ws[kk][o4] =
                    *(const float4*)&wff[((size_t)t * 128 + half * 64 + kk) * 128 + o4];
            }
            __syncthreads();
            const float (*Asrc)[36] = half ? Hs : Xs;
#pragma unroll 4
            for (int kk = 0; kk < 64; ++kk) {
                const float4 av = *(const float4*)&Asrc[kk][rg * 4];
                const float4 wv = *(const float4*)&Ws[kk][og * 4];
                const float a0 = av.x, a1 = av.y, a2 = av.z, a3 = av.w;
                acc[0][0] = fmaf(a0, wv.x, acc[0][0]); acc[0][1] = fmaf(a0, wv.y, acc[0][1]);
                acc[0][2] = fmaf(a0, wv.z, acc[0][2]); acc[0][3] = fmaf(a0, wv.w, acc[0][3]);
                acc[1][0] = fmaf(a1, wv.x, acc[1][0]); acc[1][1] = fmaf(a1, wv.y, acc[1][1]);
                acc[1][2] = fmaf(a1, wv.z, acc[1][2]); acc[1][3] = fmaf(a1, wv.w, acc[1][3]);
                acc[2][0] = fmaf(a2, wv.x, acc[2][0]); acc[2][1] = fmaf(a2, wv.y, acc[2][1]);
                acc[2][2] = fmaf(a2, wv.z, acc[2][2]); acc[2][3] = fmaf(a2, wv.w, acc[2][3]);
                acc[3][0] = fmaf(a3, wv.x, acc[3][0]); acc[3][1] = fmaf(a3, wv.y, acc[3][1]);
                acc[3][2] = fmaf(a3, wv.z, acc[3][2]); acc[3][3] = fmaf(a3, wv.w, acc[3][3]);
            }
        }
        {
            const float4 bb4 = *(const float4*)&bff[(size_t)t * 128 + og * 4];
            float g[4][4];
#pragma unroll
            for (int i = 0; i < 4; ++i) {
                g[i][0] = sigmoidf_(acc[i][0] + bb4.x);
                g[i][1] = sigmoidf_(acc[i][1] + bb4.y);
                g[i][2] = sigmoidf_(acc[i][2] + bb4.z);
                g[i][3] = sigmoidf_(acc[i][3] + bb4.w);
            }
            if (og < 16) {
#pragma unroll
                for (int i = 0; i < 4; ++i)
#pragma unroll
                    for (int j = 0; j < 4; ++j) {
                        const int f = og * 4 + j, m = rg * 4 + i;
                        Rs[f][m] = g[i][j] * Hs[f][m];
                    }
            } else {
#pragma unroll
                for (int i = 0; i < 4; ++i)
#pragma unroll
                    for (int j = 0; j < 4; ++j)
                        Us[og * 4 + j - 64][rg * 4 + i] = g[i][j];
            }
        }
        float accz[4][2];
#pragma unroll
        for (int i = 0; i < 4; ++i) { accz[i][0] = 0.0f; accz[i][1] = 0.0f; }

#pragma unroll
        for (int half = 0; half < 2; ++half) {
            __syncthreads();
#pragma unroll
            for (int p = 0; p < 4; ++p) {
                const int kk = (tid >> 4) + p * 16;
                const int f4 = (tid & 15) * 4;
                *(float4*)&Ws[kk][f4] =
                    *(const float4*)&wzff[((size_t)t * 128 + half * 64 + kk) * 64 + f4];
            }
            __syncthreads();
            const float (*Asrc)[36] = half ? Rs : Xs;
#pragma unroll 4
            for (int kk = 0; kk < 64; ++kk) {
                const float4 av = *(const float4*)&Asrc[kk][rg * 4];
                const float2 wv = *(const float2*)&Ws[kk][og * 2];
                accz[0][0] = fmaf(av.x, wv.x, accz[0][0]); accz[0][1] = fmaf(av.x, wv.y, accz[0][1]);
                accz[1][0] = fmaf(av.y, wv.x, accz[1][0]); accz[1][1] = fmaf(av.y, wv.y, accz[1][1]);
                accz[2][0] = fmaf(av.z, wv.x, accz[2][0]); accz[2][1] = fmaf(av.z, wv.y, accz[2][1]);
                accz[3][0] = fmaf(av.w, wv.x, accz[3][0]); accz[3][1] = fmaf(av.w, wv.y, accz[3][1]);
            }
        }
        {
            const float2 bz = *(const float2*)&bzff[(size_t)t * 64 + og * 2];
            const int f0_ = og * 2;
#pragma unroll
            for (int i = 0; i < 4; ++i) {
                const int m = rg * 4 + i;
                const float z0 = tanhf(accz[i][0] + bz.x);
                const float z1 = tanhf(accz[i][1] + bz.y);
                const float u0 = Us[f0_][m],     u1 = Us[f0_ + 1][m];
                const float h0 = Hs[f0_][m],     h1 = Hs[f0_ + 1][m];
                const float hn0 = u0 * z0 + (1.0f - u0) * h0;
                const float hn1 = u1 * z1 + (1.0f - u1) * h1;
                Hs[f0_][m] = hn0; Hs[f0_ + 1][m] = hn1;
                *(float2*)&out[(((size_t)b * TT + t) * NN + n0 + m) * FF + f0_] =
                    make_float2(hn0, hn1);
            }
        }
        __syncthreads();
    }
}

extern "C" void kernel_launch(void* const* d_in, const int* in_sizes, int n_in,
                              void* d_out, int out_size, void* d_ws, size_t ws_size,
                              hipStream_t stream)
{
    const float* x        = (const float*)d_in[0];
    const float* A        = (const float*)d_in[1];
    const float* conv_w   = (const float*)d_in[2];
    const float* conv_b   = (const float*)d_in[3];
    const float* bn_gamma = (const float*)d_in[4];
    const float* bn_beta  = (const float*)d_in[5];
    const float* bn_mean  = (const float*)d_in[6];
    const float* bn_var   = (const float*)d_in[7];
    const float* gru_ff_w  = (const float*)d_in[8];
    const float* gru_ff_b  = (const float*)d_in[9];
    const float* gru_zff_w = (const float*)d_in[10];
    const float* gru_zff_b = (const float*)d_in[11];
    float* out = (float*)d_out;
    char* w = (char*)d_ws;

    const size_t szA_bf  = (size_t)NB * NN * NN * 2;    // 33,554,432 B
    const size_t szXT_bf = (size_t)NB * JT * NN * 2;    // 25,165,824 B
    const size_t needFast = 2 * szA_bf + 2 * szXT_bf + 2 * szXT_bf; // 167,772,160

    dim3 gconv(8, TT, NB);

    if (ws_size >= needFast) {
        unsigned short* Ah2 = (unsigned short*)(w);
        unsigned short* Al2 = (unsigned short*)(w + szA_bf);
        unsigned short* X1h = (unsigned short*)(w + 2 * szA_bf);
        unsigned short* X1l = (unsigned short*)(w + 2 * szA_bf + szXT_bf);
        char* slot = w + 2 * szA_bf + 2 * szXT_bf;      // [117.4M, 167.77M)
        unsigned short* xh = (unsigned short*)slot;
        unsigned short* xl = (unsigned short*)(slot + szXT_bf);
        float* X2T = (float*)slot;                       // after xh/xl dead
        // post-gemm phase: y + weight images over dead Ah/Al (67.1 MB)
        float* yb = (float*)w;                           // 50.33 MB
        unsigned short* WF = (unsigned short*)(w + 50331648);          // 983,040 B
        unsigned short* WZ = (unsigned short*)(w + 50331648 + 983040); // 491,520 B

        xsplitT<<<dim3(16, TT, NB), 256, 0, stream>>>(x, xh, xl);
        split_A<<<4096, 256, 0, stream>>>(A, Ah2, Al2);
        gemm_bf<true ><<<512, 256, 0, stream>>>(Ah2, Al2, xh,  xl,  X1h, X1l, nullptr);
        gemm_bf<false><<<512, 256, 0, stream>>>(Ah2, Al2, X1h, X1l, nullptr, nullptr, X2T);
        conv_bn_relu<true><<<gconv, 256, 0, stream>>>(x, X1h, X1l, X2T, nullptr, nullptr,
                                                      conv_w, conv_b, bn_gamma, bn_beta,
                                                      bn_mean, bn_var, yb);
        wprep3<<<TT, 256, 0, stream>>>(gru_ff_w, gru_zff_w, WF, WZ);
        gru7<<<512, 256, 0, stream>>>(yb, WF, WZ, gru_ff_b, gru_zff_b, out);
    } else {
        const size_t szX = (size_t)NB * NN * JT;        // floats
        float* X1 = (float*)w;
        float* X2 = X1 + szX;
        float* yb = X2 + szX;
        gemm_f32<true ><<<768, 256, 0, stream>>>(A, x,  X1);
        gemm_f32<false><<<768, 256, 0, stream>>>(A, X1, X2);
        conv_bn_relu<false><<<gconv, 256, 0, stream>>>(x, nullptr, nullptr, nullptr, X1, X2,
                                                       conv_w, conv_b, bn_gamma, bn_beta,
                                                       bn_mean, bn_var, yb);
        gru_all<<<512, 256, 0, stream>>>(yb, gru_ff_w, gru_ff_b,
                                         gru_zff_w, gru_zff_b, out);
    }
}